// Round 1
// baseline (730.035 us; speedup 1.0000x reference)
//
#include <hip/hip_runtime.h>

typedef unsigned short u16;
typedef __attribute__((ext_vector_type(4))) unsigned short u16x4;
typedef __attribute__((ext_vector_type(8))) unsigned short u16x8;
typedef __attribute__((ext_vector_type(8))) __bf16 bf16x8;
typedef __attribute__((ext_vector_type(4))) float f32x4;

#define SLEN_ 2048
#define BSZ_ 8
#define NH_ 16
#define DH_ 64
#define IND_ 1024
#define MROWS_ (SLEN_*BSZ_)   // 16384
#define NQKV_ (NH_*3*DH_)     // 3072
#define NOUT_ (NH_*DH_)       // 1024

__device__ __forceinline__ float b2f(u16 u) {
    return __uint_as_float(((unsigned)u) << 16);
}
__device__ __forceinline__ u16 f2b(float f) {
    unsigned u = __float_as_uint(f);
    u = u + 0x7FFFu + ((u >> 16) & 1u);   // RNE
    return (u16)(u >> 16);
}

#define GLOAD_LDS16(g, l) __builtin_amdgcn_global_load_lds( \
    (const __attribute__((address_space(1))) unsigned int*)(g), \
    (__attribute__((address_space(3))) unsigned int*)(l), 16, 0, 0)

// ---------------- cast fp32 weights -> bf16 ----------------
__global__ __launch_bounds__(256) void cast_weights(
        const float* __restrict__ wq, const float* __restrict__ wo,
        u16* __restrict__ wqb, u16* __restrict__ wob)
{
    int i = blockIdx.x * 256 + threadIdx.x;
    const int NQ4 = NQKV_ * IND_ / 4;  // 786432 float4s of W_qkv
    float4 v;
    u16* dst;
    if (i < NQ4) { v = ((const float4*)wq)[i]; dst = wqb + (size_t)i * 4; }
    else { int j = i - NQ4; v = ((const float4*)wo)[j]; dst = wob + (size_t)j * 4; }
    u16x4 o;
    o[0] = f2b(v.x); o[1] = f2b(v.y); o[2] = f2b(v.z); o[3] = f2b(v.w);
    *(u16x4*)dst = o;
}

// ---------------- LayerNorm -> bf16 ----------------
__global__ __launch_bounds__(256) void ln_kernel(
        const float* __restrict__ x, const float* __restrict__ g,
        const float* __restrict__ bt, u16* __restrict__ h)
{
    int row = blockIdx.x, tid = threadIdx.x;
    const float4 v = ((const float4*)(x + (size_t)row * IND_))[tid];
    float s  = v.x + v.y + v.z + v.w;
    float s2 = v.x*v.x + v.y*v.y + v.z*v.z + v.w*v.w;
    #pragma unroll
    for (int m = 1; m < 64; m <<= 1) { s += __shfl_xor(s, m); s2 += __shfl_xor(s2, m); }
    __shared__ float sh[8];
    int w = tid >> 6, l = tid & 63;
    if (l == 0) { sh[w] = s; sh[4 + w] = s2; }
    __syncthreads();
    s  = sh[0] + sh[1] + sh[2] + sh[3];
    s2 = sh[4] + sh[5] + sh[6] + sh[7];
    float mu   = s * (1.f / IND_);
    float var  = s2 * (1.f / IND_) - mu * mu;
    float rstd = rsqrtf(var + 1e-5f);
    float4 gg = ((const float4*)g)[tid];
    float4 bb = ((const float4*)bt)[tid];
    u16x4 o;
    o[0] = f2b((v.x - mu) * rstd * gg.x + bb.x);
    o[1] = f2b((v.y - mu) * rstd * gg.y + bb.y);
    o[2] = f2b((v.z - mu) * rstd * gg.z + bb.z);
    o[3] = f2b((v.w - mu) * rstd * gg.w + bb.w);
    ((u16x4*)(h + (size_t)row * IND_))[tid] = o;
}

// ---------------- bf16 GEMM, C[M,N] = A[M,K] * B[N,K]^T ----------------
// MODE 0: store C as bf16.  MODE 1: store C as f32 with += X (residual).
template<int MODE>
__global__ __launch_bounds__(256) void gemm_bt(
        const u16* __restrict__ A, const u16* __restrict__ Bm,
        u16* __restrict__ Cb, float* __restrict__ Cf, const float* __restrict__ X,
        int M, int N, int K)
{
    __shared__ u16 As[128 * 32];
    __shared__ u16 Bs[128 * 32];
    int tid = threadIdx.x;
    int l = tid & 63, w = tid >> 6;
    int bm = blockIdx.x, bn = blockIdx.y;
    int wm = (w & 1) * 64, wn = (w >> 1) * 64;
    int fr = l & 15, fq = l >> 4;
    f32x4 acc[4][4] = {};

    int c0 = w, c1 = w + 4;                 // two 16-row chunks per wave
    const u16* a0 = A + (size_t)(bm * 128 + c0 * 16 + (l >> 2)) * K + (l & 3) * 8;
    const u16* a1 = A + (size_t)(bm * 128 + c1 * 16 + (l >> 2)) * K + (l & 3) * 8;
    const u16* b0 = Bm + (size_t)(bn * 128 + c0 * 16 + (l >> 2)) * K + (l & 3) * 8;
    const u16* b1 = Bm + (size_t)(bn * 128 + c1 * 16 + (l >> 2)) * K + (l & 3) * 8;
    u16* As0 = As + c0 * 512;  u16* As1 = As + c1 * 512;
    u16* Bs0 = Bs + c0 * 512;  u16* Bs1 = Bs + c1 * 512;

    for (int kt = 0; kt < K; kt += 32) {
        __syncthreads();                    // prev compute done before overwrite
        GLOAD_LDS16(a0 + kt, As0);
        GLOAD_LDS16(a1 + kt, As1);
        GLOAD_LDS16(b0 + kt, Bs0);
        GLOAD_LDS16(b1 + kt, Bs1);
        __syncthreads();                    // staging done (vmcnt drained)
        bf16x8 af[4], bfr[4];
        #pragma unroll
        for (int i = 0; i < 4; i++) {
            af[i]  = *(const bf16x8*)(As + (wm + i * 16 + fr) * 32 + fq * 8);
            bfr[i] = *(const bf16x8*)(Bs + (wn + i * 16 + fr) * 32 + fq * 8);
        }
        #pragma unroll
        for (int i = 0; i < 4; i++)
            #pragma unroll
            for (int j = 0; j < 4; j++)
                acc[i][j] = __builtin_amdgcn_mfma_f32_16x16x32_bf16(af[i], bfr[j], acc[i][j], 0, 0, 0);
    }

    #pragma unroll
    for (int i = 0; i < 4; i++)
        #pragma unroll
        for (int j = 0; j < 4; j++)
            #pragma unroll
            for (int r = 0; r < 4; r++) {
                int row = bm * 128 + wm + i * 16 + fq * 4 + r;
                int col = bn * 128 + wn + j * 16 + fr;
                float vv = acc[i][j][r];
                if (MODE == 0) {
                    Cb[(size_t)row * N + col] = f2b(vv);
                } else {
                    size_t idx = (size_t)row * N + col;
                    Cf[idx] = vv + X[idx];
                }
            }
}

// ---------------- fast-weight scan ----------------
// grid: 128 blocks (b*16+h), 512 threads (8 waves).
// wave w owns e-columns [w*8, w*8+8); lane: e = w*8 + (l&7), dgroup = l>>3.
// Thread holds W[d][e] for d in [dg*8, dg*8+8) -> 8 f32 regs.
__global__ __launch_bounds__(512) void scan_kernel(
        const u16* __restrict__ qkv, const float* __restrict__ state,
        u16* __restrict__ obf, float* __restrict__ wfin)
{
    __shared__ float q_lds[16][64];
    __shared__ float k_lds[16][64];
    __shared__ float v_lds[16][64];
    __shared__ float o_lds[16][64];

    int bh = blockIdx.x;
    int b = bh >> 4, hh = bh & 15;
    int tid = threadIdx.x;
    int w = tid >> 6, l = tid & 63;
    int e = (w << 3) | (l & 7);
    int dg = l >> 3;

    float wreg[8];
    #pragma unroll
    for (int j = 0; j < 8; j++)
        wreg[j] = state[(size_t)bh * 4096 + (dg * 8 + j) * 64 + e];

    for (int t0 = 0; t0 < SLEN_; t0 += 16) {
        __syncthreads();  // protect q/k/v_lds reuse; o_lds of prev chunk final
        // ---- phase A: stage 16 timesteps of raw qkv, elu+1 applied to q,k
        if (tid < 384) {
            int r = tid / 24, c = tid % 24;
            const u16x8 u = *(const u16x8*)(qkv + ((size_t)(t0 + r) * BSZ_ + b) * NQKV_ + hh * 192 + c * 8);
            float f[8];
            #pragma unroll
            for (int j = 0; j < 8; j++) f[j] = b2f(u[j]);
            if (c < 16) {
                #pragma unroll
                for (int j = 0; j < 8; j++) f[j] = f[j] > 0.f ? f[j] + 1.f : __expf(f[j]);
            }
            float* dst = (c < 8) ? &q_lds[r][c * 8]
                       : (c < 16) ? &k_lds[r][(c - 8) * 8]
                                  : &v_lds[r][(c - 16) * 8];
            float4 lo = make_float4(f[0], f[1], f[2], f[3]);
            float4 hi = make_float4(f[4], f[5], f[6], f[7]);
            *(float4*)dst = lo;
            *(float4*)(dst + 4) = hi;
        }
        // ---- flush previous chunk's o (overlapped with staging)
        if (t0 > 0) {
            int r = tid >> 5, c2 = (tid & 31) * 2;
            unsigned pack = (unsigned)f2b(o_lds[r][c2]) | ((unsigned)f2b(o_lds[r][c2 + 1]) << 16);
            *(unsigned*)(obf + ((size_t)(t0 - 16 + r) * BSZ_ + b) * NOUT_ + hh * 64 + c2) = pack;
        }
        __syncthreads();
        // ---- phase B: normalize q,k rows (sum over D=64 + 1e-5)
        {
            int row = tid >> 4, seg = tid & 15;
            float* base = (row < 16) ? &q_lds[row][seg * 4] : &k_lds[row - 16][seg * 4];
            float4 y = *(float4*)base;
            float s = y.x + y.y + y.z + y.w;
            s += __shfl_xor(s, 1); s += __shfl_xor(s, 2);
            s += __shfl_xor(s, 4); s += __shfl_xor(s, 8);
            float inv = 1.f / (s + 1e-5f);
            y.x *= inv; y.y *= inv; y.z *= inv; y.w *= inv;
            *(float4*)base = y;
        }
        __syncthreads();
        // ---- main: 16 sequential steps
        #pragma unroll
        for (int tt = 0; tt < 16; tt++) {
            float4 k0 = *(float4*)&k_lds[tt][dg * 8];
            float4 k1 = *(float4*)&k_lds[tt][dg * 8 + 4];
            float4 q0 = *(float4*)&q_lds[tt][dg * 8];
            float4 q1 = *(float4*)&q_lds[tt][dg * 8 + 4];
            float vv = v_lds[tt][e];
            float kx[8] = {k0.x, k0.y, k0.z, k0.w, k1.x, k1.y, k1.z, k1.w};
            float qx[8] = {q0.x, q0.y, q0.z, q0.w, q1.x, q1.y, q1.z, q1.w};
            #pragma unroll
            for (int j = 0; j < 8; j++) wreg[j] = fmaf(kx[j], vv, wreg[j]);
            float pa = 0.f, pb = 0.f;
            #pragma unroll
            for (int j = 0; j < 8; j += 2) {
                pa = fmaf(qx[j], wreg[j], pa);
                pb = fmaf(qx[j + 1], wreg[j + 1], pb);
            }
            float p = pa + pb;
            p += __shfl_xor(p, 8); p += __shfl_xor(p, 16); p += __shfl_xor(p, 32);
            if (dg == 0) o_lds[tt][e] = p;   // lanes l<8 -> e = w*8+l
        }
    }
    __syncthreads();
    // final o chunk flush
    {
        int r = tid >> 5, c2 = (tid & 31) * 2;
        unsigned pack = (unsigned)f2b(o_lds[r][c2]) | ((unsigned)f2b(o_lds[r][c2 + 1]) << 16);
        *(unsigned*)(obf + ((size_t)(SLEN_ - 16 + r) * BSZ_ + b) * NOUT_ + hh * 64 + c2) = pack;
    }
    // W_final
    #pragma unroll
    for (int j = 0; j < 8; j++)
        wfin[(size_t)bh * 4096 + (dg * 8 + j) * 64 + e] = wreg[j];
}

extern "C" void kernel_launch(void* const* d_in, const int* in_sizes, int n_in,
                              void* d_out, int out_size, void* d_ws, size_t ws_size,
                              hipStream_t stream) {
    const float* x     = (const float*)d_in[0];
    const float* state = (const float*)d_in[1];
    const float* wqkv  = (const float*)d_in[2];
    const float* wout  = (const float*)d_in[3];
    const float* gamma = (const float*)d_in[4];
    const float* beta  = (const float*)d_in[5];

    float* out0 = (float*)d_out;                       // [2048,8,1024] f32
    float* wfin = (float*)d_out + (size_t)MROWS_ * IND_; // [8,16,64,64] f32

    char* ws = (char*)d_ws;
    u16* qkv_bf = (u16*)ws;                                        // 96 MB
    u16* h_bf   = (u16*)(ws + 100663296);                          // 32 MB
    u16* o_bf   = h_bf;                                            // reuse (h dead after GEMM1)
    u16* wq_bf  = (u16*)(ws + 100663296 + 33554432);               // 6 MB
    u16* wo_bf  = (u16*)(ws + 100663296 + 33554432 + 6291456);     // 2 MB

    cast_weights<<<4096, 256, 0, stream>>>(wqkv, wout, wq_bf, wo_bf);
    ln_kernel<<<MROWS_, 256, 0, stream>>>(x, gamma, beta, h_bf);
    dim3 g1(MROWS_ / 128, NQKV_ / 128);
    gemm_bt<0><<<g1, 256, 0, stream>>>(h_bf, wq_bf, qkv_bf, nullptr, nullptr, MROWS_, NQKV_, IND_);
    scan_kernel<<<128, 512, 0, stream>>>(qkv_bf, state, o_bf, wfin);
    dim3 g2(MROWS_ / 128, NOUT_ / 128);
    gemm_bt<1><<<g2, 256, 0, stream>>>(o_bf, wo_bf, nullptr, out0, x, MROWS_, NOUT_, IND_);
}

// Round 2
// 351.179 us; speedup vs baseline: 2.0788x; 2.0788x over previous
//
#include <hip/hip_runtime.h>

typedef unsigned short u16;
typedef __attribute__((ext_vector_type(4))) unsigned short u16x4;
typedef __attribute__((ext_vector_type(8))) unsigned short u16x8;
typedef __attribute__((ext_vector_type(8))) __bf16 bf16x8;
typedef __attribute__((ext_vector_type(4))) float f32x4;

#define SLEN_ 2048
#define BSZ_ 8
#define NH_ 16
#define DH_ 64
#define IND_ 1024
#define MROWS_ (SLEN_*BSZ_)   // 16384
#define NQKV_ (NH_*3*DH_)     // 3072
#define NOUT_ (NH_*DH_)       // 1024

__device__ __forceinline__ float b2f(u16 u) {
    return __uint_as_float(((unsigned)u) << 16);
}
__device__ __forceinline__ u16 f2b(float f) {
    unsigned u = __float_as_uint(f);
    u = u + 0x7FFFu + ((u >> 16) & 1u);   // RNE
    return (u16)(u >> 16);
}

#define GLOAD_LDS16(g, l) __builtin_amdgcn_global_load_lds( \
    (const __attribute__((address_space(1))) unsigned int*)(g), \
    (__attribute__((address_space(3))) unsigned int*)(l), 16, 0, 0)

// swizzled LDS byte offset for [64][64] bf16 tiles (row stride 128 B)
#define TI(r, c) ((((r) << 7) + ((c) << 1)) ^ (((r) & 7) << 4))

// ---------------- cast fp32 weights -> bf16 ----------------
__global__ __launch_bounds__(256) void cast_weights(
        const float* __restrict__ wq, const float* __restrict__ wo,
        u16* __restrict__ wqb, u16* __restrict__ wob)
{
    int i = blockIdx.x * 256 + threadIdx.x;
    const int NQ4 = NQKV_ * IND_ / 4;
    float4 v;
    u16* dst;
    if (i < NQ4) { v = ((const float4*)wq)[i]; dst = wqb + (size_t)i * 4; }
    else { int j = i - NQ4; v = ((const float4*)wo)[j]; dst = wob + (size_t)j * 4; }
    u16x4 o;
    o[0] = f2b(v.x); o[1] = f2b(v.y); o[2] = f2b(v.z); o[3] = f2b(v.w);
    *(u16x4*)dst = o;
}

// ---------------- LayerNorm -> bf16 ----------------
__global__ __launch_bounds__(256) void ln_kernel(
        const float* __restrict__ x, const float* __restrict__ g,
        const float* __restrict__ bt, u16* __restrict__ h)
{
    int row = blockIdx.x, tid = threadIdx.x;
    const float4 v = ((const float4*)(x + (size_t)row * IND_))[tid];
    float s  = v.x + v.y + v.z + v.w;
    float s2 = v.x*v.x + v.y*v.y + v.z*v.z + v.w*v.w;
    #pragma unroll
    for (int m = 1; m < 64; m <<= 1) { s += __shfl_xor(s, m); s2 += __shfl_xor(s2, m); }
    __shared__ float sh[8];
    int w = tid >> 6, l = tid & 63;
    if (l == 0) { sh[w] = s; sh[4 + w] = s2; }
    __syncthreads();
    s  = sh[0] + sh[1] + sh[2] + sh[3];
    s2 = sh[4] + sh[5] + sh[6] + sh[7];
    float mu   = s * (1.f / IND_);
    float var  = s2 * (1.f / IND_) - mu * mu;
    float rstd = rsqrtf(var + 1e-5f);
    float4 gg = ((const float4*)g)[tid];
    float4 bb = ((const float4*)bt)[tid];
    u16x4 o;
    o[0] = f2b((v.x - mu) * rstd * gg.x + bb.x);
    o[1] = f2b((v.y - mu) * rstd * gg.y + bb.y);
    o[2] = f2b((v.z - mu) * rstd * gg.z + bb.z);
    o[3] = f2b((v.w - mu) * rstd * gg.w + bb.w);
    ((u16x4*)(h + (size_t)row * IND_))[tid] = o;
}

// ---------------- bf16 GEMM, C[M,N] = A[M,K] * B[N,K]^T ----------------
template<int MODE>
__global__ __launch_bounds__(256) void gemm_bt(
        const u16* __restrict__ A, const u16* __restrict__ Bm,
        u16* __restrict__ Cb, float* __restrict__ Cf, const float* __restrict__ X,
        int M, int N, int K)
{
    __shared__ u16 As[128 * 32];
    __shared__ u16 Bs[128 * 32];
    int tid = threadIdx.x;
    int l = tid & 63, w = tid >> 6;
    int bm = blockIdx.x, bn = blockIdx.y;
    int wm = (w & 1) * 64, wn = (w >> 1) * 64;
    int fr = l & 15, fq = l >> 4;
    f32x4 acc[4][4] = {};

    int c0 = w, c1 = w + 4;
    const u16* a0 = A + (size_t)(bm * 128 + c0 * 16 + (l >> 2)) * K + (l & 3) * 8;
    const u16* a1 = A + (size_t)(bm * 128 + c1 * 16 + (l >> 2)) * K + (l & 3) * 8;
    const u16* b0 = Bm + (size_t)(bn * 128 + c0 * 16 + (l >> 2)) * K + (l & 3) * 8;
    const u16* b1 = Bm + (size_t)(bn * 128 + c1 * 16 + (l >> 2)) * K + (l & 3) * 8;
    u16* As0 = As + c0 * 512;  u16* As1 = As + c1 * 512;
    u16* Bs0 = Bs + c0 * 512;  u16* Bs1 = Bs + c1 * 512;

    for (int kt = 0; kt < K; kt += 32) {
        __syncthreads();
        GLOAD_LDS16(a0 + kt, As0);
        GLOAD_LDS16(a1 + kt, As1);
        GLOAD_LDS16(b0 + kt, Bs0);
        GLOAD_LDS16(b1 + kt, Bs1);
        __syncthreads();
        bf16x8 af[4], bfr[4];
        #pragma unroll
        for (int i = 0; i < 4; i++) {
            af[i]  = *(const bf16x8*)(As + (wm + i * 16 + fr) * 32 + fq * 8);
            bfr[i] = *(const bf16x8*)(Bs + (wn + i * 16 + fr) * 32 + fq * 8);
        }
        #pragma unroll
        for (int i = 0; i < 4; i++)
            #pragma unroll
            for (int j = 0; j < 4; j++)
                acc[i][j] = __builtin_amdgcn_mfma_f32_16x16x32_bf16(af[i], bfr[j], acc[i][j], 0, 0, 0);
    }

    #pragma unroll
    for (int i = 0; i < 4; i++)
        #pragma unroll
        for (int j = 0; j < 4; j++)
            #pragma unroll
            for (int r = 0; r < 4; r++) {
                int row = bm * 128 + wm + i * 16 + fq * 4 + r;
                int col = bn * 128 + wn + j * 16 + fr;
                float vv = acc[i][j][r];
                if (MODE == 0) {
                    Cb[(size_t)row * N + col] = f2b(vv);
                } else {
                    size_t idx = (size_t)row * N + col;
                    Cf[idx] = vv + X[idx];
                }
            }
}

// ---------------- chunked fast-weight scan (chunk C=64, MFMA) ----------------
// grid 128 = (b,h); 256 threads = 4 waves. Per chunk:
//   St = K·Q^T (St[s][t]); P[t][s] = tril-masked St, bf16
//   O  = P·V + Q·W_prev ; Wt[e][d] += V^T·K  (accW = persistent f32 fragments)
// LDS tiles (all XOR-swizzled): Q[t][d], K[s][d], Kt[d][t], Vt[e][s], P[t][s], W_l[e][d].
// P_l doubles as O_lds after P is consumed (barrier-separated).
__global__ __launch_bounds__(256) void scan2(
        const u16* __restrict__ qkv, const float* __restrict__ state,
        u16* __restrict__ obf, float* __restrict__ wfin)
{
    __shared__ u16 Q_l[4096], K_l[4096], Kt_l[4096], Vt_l[4096], P_l[4096], W_l[4096];

    const int bh = blockIdx.x;
    const int b = bh >> 4, hh = bh & 15;
    const int tid = threadIdx.x;
    const int w = tid >> 6, l = tid & 63;
    const int fr = l & 15, fq = l >> 4;

    // init W state (accumulators hold Wt[e][d] = W[d][e]; W_l is bf16 copy)
    f32x4 accW[4];
    #pragma unroll
    for (int jt = 0; jt < 4; jt++) {
        #pragma unroll
        for (int r = 0; r < 4; r++) {
            int d = jt * 16 + fr, e = w * 16 + fq * 4 + r;
            float sv = state[(size_t)bh * 4096 + d * 64 + e];
            accW[jt][r] = sv;
            *(u16*)((char*)W_l + TI(e, d)) = f2b(sv);
        }
    }

    // per-wave staging role: w0=q rows, w1=k rows, w2/w3=v half-rows
    int goff = (w == 0) ? 0 : (w == 1) ? 64 : (w == 2) ? 128 : 160;
    const u16* g0 = qkv + ((size_t)l * BSZ_ + b) * NQKV_ + hh * 192 + goff;
    const size_t chunk_stride = (size_t)64 * BSZ_ * NQKV_;

    u16x8 pre[8];
    if (w < 2) {
        #pragma unroll
        for (int j = 0; j < 8; j++) pre[j] = *(const u16x8*)(g0 + j * 8);
    } else {
        #pragma unroll
        for (int j = 0; j < 4; j++) pre[j] = *(const u16x8*)(g0 + j * 8);
    }

    __syncthreads();  // W_l init visible

    #pragma unroll 1
    for (int n = 0; n < 32; n++) {
        // ---- process staged regs -> LDS (elu+1, row-normalize q,k; transpose k,v)
        if (w < 2) {
            float f[64];
            #pragma unroll
            for (int j = 0; j < 8; j++)
                #pragma unroll
                for (int m = 0; m < 8; m++) {
                    float x = b2f(pre[j][m]);
                    f[j * 8 + m] = x > 0.f ? x + 1.f : __expf(x);
                }
            float s = 0.f;
            #pragma unroll
            for (int i = 0; i < 64; i++) s += f[i];
            float inv = 1.f / (s + 1e-5f);
            u16* dst = (w == 0) ? Q_l : K_l;
            #pragma unroll
            for (int j = 0; j < 8; j++) {
                u16x8 o;
                #pragma unroll
                for (int m = 0; m < 8; m++) o[m] = f2b(f[j * 8 + m] * inv);
                *(u16x8*)((char*)dst + TI(l, j * 8)) = o;
                if (w == 1) {
                    #pragma unroll
                    for (int m = 0; m < 8; m++)
                        *(u16*)((char*)Kt_l + TI(j * 8 + m, l)) = o[m];
                }
            }
        } else {
            int e0 = (w == 2) ? 0 : 32;
            #pragma unroll
            for (int j = 0; j < 4; j++)
                #pragma unroll
                for (int m = 0; m < 8; m++)
                    *(u16*)((char*)Vt_l + TI(e0 + j * 8 + m, l)) = pre[j][m];
        }
        __syncthreads();

        // ---- prefetch next chunk (overlaps all compute below)
        if (n < 31) {
            const u16* gn = g0 + (size_t)(n + 1) * chunk_stride;
            if (w < 2) {
                #pragma unroll
                for (int j = 0; j < 8; j++) pre[j] = *(const u16x8*)(gn + j * 8);
            } else {
                #pragma unroll
                for (int j = 0; j < 4; j++) pre[j] = *(const u16x8*)(gn + j * 8);
            }
        }

        // ---- St = K·Q^T (wave owns rows s = w*16..)
        f32x4 aS[4] = {};
        bf16x8 aK[2];
        #pragma unroll
        for (int ks = 0; ks < 2; ks++)
            aK[ks] = *(const bf16x8*)((const char*)K_l + TI(w * 16 + fr, ks * 32 + fq * 8));
        #pragma unroll
        for (int jt = 0; jt < 4; jt++)
            #pragma unroll
            for (int ks = 0; ks < 2; ks++) {
                bf16x8 bq = *(const bf16x8*)((const char*)Q_l + TI(jt * 16 + fr, ks * 32 + fq * 8));
                aS[jt] = __builtin_amdgcn_mfma_f32_16x16x32_bf16(aK[ks], bq, aS[jt], 0, 0, 0);
            }
        // mask (keep s<=t), cvt bf16, write P[t][s] (contiguous b64 per lane)
        #pragma unroll
        for (int jt = 0; jt < 4; jt++) {
            int t = jt * 16 + fr;
            int s0 = w * 16 + fq * 4;
            unsigned pk0, pk1;
            {
                u16 e0 = (s0 + 0 <= t) ? f2b(aS[jt][0]) : (u16)0;
                u16 e1 = (s0 + 1 <= t) ? f2b(aS[jt][1]) : (u16)0;
                u16 e2 = (s0 + 2 <= t) ? f2b(aS[jt][2]) : (u16)0;
                u16 e3 = (s0 + 3 <= t) ? f2b(aS[jt][3]) : (u16)0;
                pk0 = (unsigned)e0 | ((unsigned)e1 << 16);
                pk1 = (unsigned)e2 | ((unsigned)e3 << 16);
            }
            uint2 pkk; pkk.x = pk0; pkk.y = pk1;
            *(uint2*)((char*)P_l + TI(t, s0)) = pkk;
        }
        __syncthreads();

        // ---- O = P·V + Q·W_prev ; accW += V^T·K   (wave owns rows w*16..)
        f32x4 aO[4] = {};
        bf16x8 ap[2], aq2[2], av[2];
        #pragma unroll
        for (int ks = 0; ks < 2; ks++) {
            ap[ks]  = *(const bf16x8*)((const char*)P_l  + TI(w * 16 + fr, ks * 32 + fq * 8));
            aq2[ks] = *(const bf16x8*)((const char*)Q_l  + TI(w * 16 + fr, ks * 32 + fq * 8));
            av[ks]  = *(const bf16x8*)((const char*)Vt_l + TI(w * 16 + fr, ks * 32 + fq * 8));
        }
        #pragma unroll
        for (int jt = 0; jt < 4; jt++) {
            #pragma unroll
            for (int ks = 0; ks < 2; ks++) {
                bf16x8 bv = *(const bf16x8*)((const char*)Vt_l + TI(jt * 16 + fr, ks * 32 + fq * 8));
                aO[jt] = __builtin_amdgcn_mfma_f32_16x16x32_bf16(ap[ks], bv, aO[jt], 0, 0, 0);
            }
            #pragma unroll
            for (int ks = 0; ks < 2; ks++) {
                bf16x8 bw = *(const bf16x8*)((const char*)W_l + TI(jt * 16 + fr, ks * 32 + fq * 8));
                aO[jt] = __builtin_amdgcn_mfma_f32_16x16x32_bf16(aq2[ks], bw, aO[jt], 0, 0, 0);
            }
            #pragma unroll
            for (int ks = 0; ks < 2; ks++) {
                bf16x8 bk = *(const bf16x8*)((const char*)Kt_l + TI(jt * 16 + fr, ks * 32 + fq * 8));
                accW[jt] = __builtin_amdgcn_mfma_f32_16x16x32_bf16(av[ks], bk, accW[jt], 0, 0, 0);
            }
        }
        __syncthreads();

        // ---- write updated W_l (bf16) and O (bf16) into P_l (now O_lds)
        #pragma unroll
        for (int jt = 0; jt < 4; jt++)
            #pragma unroll
            for (int r = 0; r < 4; r++) {
                int e = w * 16 + fq * 4 + r, d = jt * 16 + fr;
                *(u16*)((char*)W_l + TI(e, d)) = f2b(accW[jt][r]);
                *(u16*)((char*)P_l + TI(e, d)) = f2b(aO[jt][r]);  // t=e idx, e-col=d idx roles
            }
        __syncthreads();

        // ---- coalesced O global write
        {
            int t = tid >> 2, seg = tid & 3;
            u16x8 o1 = *(const u16x8*)((const char*)P_l + TI(t, seg * 16));
            u16x8 o2 = *(const u16x8*)((const char*)P_l + TI(t, seg * 16 + 8));
            u16* gd = obf + ((size_t)(n * 64 + t) * BSZ_ + b) * NOUT_ + hh * 64 + seg * 16;
            *(u16x8*)(gd) = o1;
            *(u16x8*)(gd + 8) = o2;
        }
    }

    // ---- W_final (f32, from accumulators)
    #pragma unroll
    for (int jt = 0; jt < 4; jt++)
        #pragma unroll
        for (int r = 0; r < 4; r++) {
            int d = jt * 16 + fr, e = w * 16 + fq * 4 + r;
            wfin[(size_t)bh * 4096 + d * 64 + e] = accW[jt][r];
        }
}

extern "C" void kernel_launch(void* const* d_in, const int* in_sizes, int n_in,
                              void* d_out, int out_size, void* d_ws, size_t ws_size,
                              hipStream_t stream) {
    const float* x     = (const float*)d_in[0];
    const float* state = (const float*)d_in[1];
    const float* wqkv  = (const float*)d_in[2];
    const float* wout  = (const float*)d_in[3];
    const float* gamma = (const float*)d_in[4];
    const float* beta  = (const float*)d_in[5];

    float* out0 = (float*)d_out;
    float* wfin = (float*)d_out + (size_t)MROWS_ * IND_;

    char* ws = (char*)d_ws;
    u16* qkv_bf = (u16*)ws;
    u16* h_bf   = (u16*)(ws + 100663296);
    u16* o_bf   = h_bf;
    u16* wq_bf  = (u16*)(ws + 100663296 + 33554432);
    u16* wo_bf  = (u16*)(ws + 100663296 + 33554432 + 6291456);

    cast_weights<<<4096, 256, 0, stream>>>(wqkv, wout, wq_bf, wo_bf);
    ln_kernel<<<MROWS_, 256, 0, stream>>>(x, gamma, beta, h_bf);
    dim3 g1(MROWS_ / 128, NQKV_ / 128);
    gemm_bt<0><<<g1, 256, 0, stream>>>(h_bf, wq_bf, qkv_bf, nullptr, nullptr, MROWS_, NQKV_, IND_);
    scan2<<<128, 256, 0, stream>>>(qkv_bf, state, o_bf, wfin);
    dim3 g2(MROWS_ / 128, NOUT_ / 128);
    gemm_bt<1><<<g2, 256, 0, stream>>>(o_bf, wo_bf, nullptr, out0, x, MROWS_, NOUT_, IND_);
}